// Round 11
// baseline (189.670 us; speedup 1.0000x reference)
//
#include <hip/hip_runtime.h>
#include <cstdint>

#define NB   32
#define CIN  128
#define HH   56
#define WW   56
#define KOUT 256
#define HWS  (HH*WW)            // 3136
#define NHW  (NB*HWS)           // 100352
#define XCNT ((float)(NB*CIN*HWS))
#define WCNT ((float)(KOUT*CIN*9))
#define PR   58                 // padded rows/cols 0..57 (interior at +1)
#define XROW (PR*CIN)           // 7424 B per padded row
#define XIMG ((size_t)PR*PR*CIN)// 430592 B per image
#define XP8SZ ((size_t)NB*XIMG) // 13778944 B
#define WTAP ((size_t)KOUT*CIN) // 32768 B per tap plane

typedef int i32x4 __attribute__((ext_vector_type(4)));

__device__ __forceinline__ void block_reduce_add(float v, float* dst) {
    #pragma unroll
    for (int off = 32; off > 0; off >>= 1) v += __shfl_down(v, off);
    __shared__ float ws4[4];
    int lane = threadIdx.x & 63, wid = threadIdx.x >> 6;
    if (lane == 0) ws4[wid] = v;
    __syncthreads();
    if (threadIdx.x == 0) {
        float s = ws4[0];
        int nw = (blockDim.x + 63) >> 6;
        for (int i = 1; i < nw; i++) s += ws4[i];
        atomicAdd(dst, s);
    }
}

// Block = (n,h). Unit u = (cq, w): read 4 floats (coalesced along w per c),
// write one u32 of 4 sign-bytes into padded NHWC i8 (pads stay memset-zero).
__global__ __launch_bounds__(256) void pack_x_kernel(const float* __restrict__ x,
                                                     char* __restrict__ xp8,
                                                     float* __restrict__ sums) {
    int bid = blockIdx.x;
    int n = bid / HH, h = bid - n * HH;
    const float* xn = x + (size_t)n * CIN * HWS + h * WW;
    char* xw = xp8 + (size_t)n * XIMG + (size_t)(h + 1) * XROW + CIN;  // row h+1, col +1
    float asum = 0.f;
    #pragma unroll 1
    for (int it = 0; it < 7; it++) {
        int u  = it * 256 + threadIdx.x;                   // 0..1791
        int cq = (int)(((unsigned)u * 9363u) >> 19);       // u / 56 (exact, u<13107)
        int w  = u - cq * 56;
        uint32_t bits = 0;
        #pragma unroll
        for (int i = 0; i < 4; i++) {
            float v = xn[(size_t)(cq * 4 + i) * HWS + w];
            asum += fabsf(v);
            bits |= ((v > 0.f) ? 0x01u : 0xFFu) << (8 * i);
        }
        *(uint32_t*)(xw + (size_t)w * CIN + cq * 4) = bits;
    }
    block_reduce_add(asum, &sums[0]);
}

// Unit = (k, tap): read 128 channels (stride 9), write 128 contiguous i8
// at wp8[tap][k][c]. Grid 9 x 256.
__global__ __launch_bounds__(256) void pack_w_kernel(const float* __restrict__ wgt,
                                                     char* __restrict__ wp8,
                                                     float* __restrict__ sums) {
    int u = blockIdx.x * 256 + threadIdx.x;                // 0..2303
    int k = (int)(((unsigned)u * 29128u) >> 18);           // u / 9 (exact, u<32768)
    int t = u - k * 9;
    const float* wk = wgt + (size_t)k * CIN * 9 + t;
    float asum = 0.f;
    uint32_t wd[32];
    #pragma unroll
    for (int c = 0; c < 128; c++) {
        float v = wk[(size_t)c * 9];
        asum += fabsf(v);
        uint32_t b = (v > 0.f) ? 0x01u : 0xFFu;
        if ((c & 3) == 0) wd[c >> 2] = b;
        else              wd[c >> 2] |= b << (8 * (c & 3));
    }
    uint4* dst = (uint4*)(wp8 + ((size_t)t * KOUT + k) * CIN);
    #pragma unroll
    for (int cw = 0; cw < 8; cw++)
        dst[cw] = make_uint4(wd[cw*4], wd[cw*4+1], wd[cw*4+2], wd[cw*4+3]);
    block_reduce_add(asum, &sums[1]);
}

// Implicit-GEMM binary conv via __builtin_amdgcn_mfma_i32_16x16x64_i8.
// Block = 4 independent waves; wave = 32 k-channels (2 M-tiles, A resident
// in 144 VGPRs) x 7 N-tiles of 16 flat spatial positions. Per tile: 18
// B-frag loads (16B/lane = 16 NHWC channels) -> 36 MFMAs. Builtin (not asm)
// so the compiler manages MFMA->VALU hazards (R10's bug: hand-rolled s_nop
// only covered acc1; acc0's v_cvt was scheduled into the hazard window).
// Zero-padded NHWC buffer makes conv padding exact; K-placement identical
// for A and B so any HW K-permutation cancels.
__global__ __launch_bounds__(256) void conv_kernel(const char* __restrict__ xp8,
                                                   const char* __restrict__ wp8,
                                                   const float* __restrict__ sums,
                                                   const float* __restrict__ bias,
                                                   float* __restrict__ out) {
    int bid = blockIdx.x;
    int sw  = (bid & 7) * 224 + (bid >> 3);   // XCD-bijective swizzle (1792 = 8*224)
    int n   = sw / 56;
    int rem = sw - n * 56;
    int kb  = rem / 28;                        // 0..1
    int g   = rem - kb * 28;                   // 0..27 position group (112 pos)

    int tid = threadIdx.x;
    int l = tid & 63, wid = tid >> 6;
    int k0 = kb * 128 + wid * 32;
    int row = l & 15, q = l >> 4;

    // A fragments: lane = W[k0 + mtile*16 + row][tap t, channels q*16 + c*64 ..+16)
    const char* Ab = wp8 + (size_t)(k0 + row) * CIN + q * 16;
    i32x4 A0[18], A1[18];
    #pragma unroll
    for (int t = 0; t < 9; t++) {
        #pragma unroll
        for (int c = 0; c < 2; c++) {
            A0[t*2+c] = *(const i32x4*)(Ab + (size_t)t * WTAP + c * 64);
            A1[t*2+c] = *(const i32x4*)(Ab + (size_t)t * WTAP + 16 * CIN + c * 64);
        }
    }

    float scale = (sums[0] * (1.0f / XCNT)) * (sums[1] * (1.0f / WCNT));
    float bv0[4], bv1[4];
    #pragma unroll
    for (int r = 0; r < 4; r++) {
        bv0[r] = bias[k0 + q*4 + r];
        bv1[r] = bias[k0 + 16 + q*4 + r];
    }
    float* o0[4]; float* o1[4];
    size_t obase = (size_t)(n * KOUT + k0 + q*4) * HWS + g * 112 + (l & 15);
    #pragma unroll
    for (int r = 0; r < 4; r++) {
        o0[r] = out + obase + (size_t)r * HWS;
        o1[r] = out + obase + (size_t)(16 + r) * HWS;
    }

    const char* xpn = xp8 + (size_t)n * XIMG + q * 16;

    #pragma unroll 1
    for (int j = 0; j < 7; j++) {
        int pos = g * 112 + j * 16 + (l & 15);
        int h   = (int)(((unsigned)pos * 9363u) >> 19);    // pos / 56
        int w   = pos - h * 56;
        // tap (dy,dx) reads padded (h+dy, w+dx); dy via row pointers, dx/c via imm
        const char* b0 = xpn + (size_t)h * XROW + (size_t)w * CIN;
        const char* b1 = b0 + XROW;
        const char* b2 = b0 + 2 * XROW;
        i32x4 acc0 = {0,0,0,0}, acc1 = {0,0,0,0};
#define STEP(BP, DX, T, C) { i32x4 bq = *(const i32x4*)((BP) + (DX)*CIN + (C)*64); \
        acc0 = __builtin_amdgcn_mfma_i32_16x16x64_i8(A0[(T)*2+(C)], bq, acc0, 0, 0, 0); \
        acc1 = __builtin_amdgcn_mfma_i32_16x16x64_i8(A1[(T)*2+(C)], bq, acc1, 0, 0, 0); }
        STEP(b0,0,0,0) STEP(b0,0,0,1) STEP(b0,1,1,0) STEP(b0,1,1,1) STEP(b0,2,2,0) STEP(b0,2,2,1)
        STEP(b1,0,3,0) STEP(b1,0,3,1) STEP(b1,1,4,0) STEP(b1,1,4,1) STEP(b1,2,5,0) STEP(b1,2,5,1)
        STEP(b2,0,6,0) STEP(b2,0,6,1) STEP(b2,1,7,0) STEP(b2,1,7,1) STEP(b2,2,8,0) STEP(b2,2,8,1)
#undef STEP
        #pragma unroll
        for (int r = 0; r < 4; r++) {
            o0[r][j*16] = fmaf(scale, (float)acc0[r], bv0[r]);
            o1[r][j*16] = fmaf(scale, (float)acc1[r], bv1[r]);
        }
    }
}

extern "C" void kernel_launch(void* const* d_in, const int* in_sizes, int n_in,
                              void* d_out, int out_size, void* d_ws, size_t ws_size,
                              hipStream_t stream) {
    const float* x    = (const float*)d_in[0];
    const float* wgt  = (const float*)d_in[1];
    const float* bias = (const float*)d_in[2];
    float* out = (float*)d_out;

    // ws: sums[2] (256B) | xp8 padded NHWC i8 (13.78 MB) | wp8 [tap][k][c] (288 KB)
    float* sums = (float*)d_ws;
    char*  xp8  = (char*)d_ws + 256;
    char*  wp8  = (char*)d_ws + 256 + XP8SZ;

    hipMemsetAsync(d_ws, 0, 256 + XP8SZ, stream);   // zeroes sums + all pad borders
    hipLaunchKernelGGL(pack_w_kernel, dim3(9), dim3(256), 0, stream, wgt, wp8, sums);
    hipLaunchKernelGGL(pack_x_kernel, dim3(NB * HH), dim3(256), 0, stream, x, xp8, sums);
    hipLaunchKernelGGL(conv_kernel, dim3(NB * HH), dim3(256), 0, stream,
                       xp8, wp8, sums, bias, out);
}